// Round 1
// baseline (242.610 us; speedup 1.0000x reference)
//
#include <hip/hip_runtime.h>
#include <cstdint>
#include <cstddef>

// ---------------- problem constants ----------------
constexpr int CB  = 8;     // batch
constexpr int CS  = 512;   // seq len
constexpr int CH  = 768;   // hidden
constexpr int CNH = 12;    // heads
constexpr int CDH = 64;    // head dim
constexpr int CFF = 3072;  // ffn dim
constexpr int CE  = 4;     // experts

using f32x4  = __attribute__((ext_vector_type(4))) float;
using bf16x8 = __attribute__((ext_vector_type(8))) short;

__device__ __forceinline__ short f2bf(float x) {
  union { float f; uint32_t u; } v; v.f = x;
  return (short)((v.u + 0x7fffu + ((v.u >> 16) & 1u)) >> 16);  // RNE
}

__device__ __forceinline__ void gload_lds16(const void* g, void* l) {
  __builtin_amdgcn_global_load_lds((const __attribute__((address_space(1))) void*)g,
                                   (__attribute__((address_space(3))) void*)l,
                                   16, 0, 0);
}

// ---------------- fp32 -> bf16 elementwise ----------------
__global__ void cvt_bf16_kernel(const float* __restrict__ in, short* __restrict__ out, int n4) {
  int i = blockIdx.x * blockDim.x + threadIdx.x;
  if (i < n4) {
    float4 v = ((const float4*)in)[i];
    short4 o;
    o.x = f2bf(v.x); o.y = f2bf(v.y); o.z = f2bf(v.z); o.w = f2bf(v.w);
    ((short4*)out)[i] = o;
  }
}

// ---------------- W [E,K,N] fp32 -> Wt [E,N,K] bf16 (transpose + convert) ----
// grid: (N/64, K/64, E), block 256
__global__ void tpose_cvt_kernel(const float* __restrict__ W, short* __restrict__ Wt,
                                 int K, int N) {
  __shared__ __align__(16) short Ts[64 * 68];
  const int e  = blockIdx.z;
  const int n0 = blockIdx.x * 64, k0 = blockIdx.y * 64;
  const float* Wb = W + (size_t)e * K * N;
  short* Wtb = Wt + (size_t)e * K * N;
  const int t  = threadIdx.x;
  const int tn = t & 15, tk = t >> 4;  // tn: 0..15, tk: 0..15
#pragma unroll
  for (int p = 0; p < 4; ++p) {
    int k = k0 + p * 16 + tk;
    float4 v = *(const float4*)(Wb + (size_t)k * N + n0 + tn * 4);
#pragma unroll
    for (int j = 0; j < 4; ++j)
      Ts[(tn * 4 + j) * 68 + p * 16 + tk] = f2bf(((const float*)&v)[j]);
  }
  __syncthreads();
#pragma unroll
  for (int p = 0; p < 4; ++p) {
    int n = n0 + p * 16 + tk;
    uint2 o = *(const uint2*)(Ts + (p * 16 + tk) * 68 + tn * 4);
    *(uint2*)(Wtb + (size_t)n * K + k0 + tn * 4) = o;
  }
}

// ---------------- GEMM core: out[512,N] = act(A[512,K] @ W^T(stored [N,K]) + bias) ----
// m97 structure: 128x128 tile, BK=32, 4 waves (2x2 of 64x64), global_load_lds staging.
template <int K, int ACT, bool OB16>
__device__ __forceinline__ void gemm_tile(const short* __restrict__ A,   // sample base [512,K]
                                          const short* __restrict__ Wt,  // expert base [N,K]
                                          const float* __restrict__ bias,// expert base [N]
                                          void* out,                     // sample base [512,N]
                                          int N, int mt, int nt) {
  __shared__ __align__(16) short As[128 * 32];
  __shared__ __align__(16) short Bs[128 * 32];
  const int t = threadIdx.x;
  const int w = t >> 6, l = t & 63;
  const int lr = l & 15, lg = l >> 4;

  const short* aS0 = A  + (size_t)(mt * 128 +      w * 16 + (l >> 2)) * K + (l & 3) * 8;
  const short* aS1 = A  + (size_t)(mt * 128 + 64 + w * 16 + (l >> 2)) * K + (l & 3) * 8;
  const short* bS0 = Wt + (size_t)(nt * 128 +      w * 16 + (l >> 2)) * K + (l & 3) * 8;
  const short* bS1 = Wt + (size_t)(nt * 128 + 64 + w * 16 + (l >> 2)) * K + (l & 3) * 8;
  short* aD0 = As +        w * 512 + l * 8;
  short* aD1 = As + 2048 + w * 512 + l * 8;
  short* bD0 = Bs +        w * 512 + l * 8;
  short* bD1 = Bs + 2048 + w * 512 + l * 8;

  const int wr = w >> 1, wc = w & 1;
  f32x4 acc[4][4] = {};
  int aoff[4], boff[4];
#pragma unroll
  for (int i = 0; i < 4; ++i) {
    aoff[i] = (wr * 64 + i * 16 + lr) * 32 + lg * 8;
    boff[i] = (wc * 64 + i * 16 + lr) * 32 + lg * 8;
  }

  for (int kk = 0; kk < K / 32; ++kk) {
    gload_lds16(aS0, aD0);
    gload_lds16(aS1, aD1);
    gload_lds16(bS0, bD0);
    gload_lds16(bS1, bD1);
    aS0 += 32; aS1 += 32; bS0 += 32; bS1 += 32;
    __syncthreads();
    bf16x8 af[4], bfr[4];
#pragma unroll
    for (int i = 0; i < 4; ++i) {
      af[i]  = *(const bf16x8*)(As + aoff[i]);
      bfr[i] = *(const bf16x8*)(Bs + boff[i]);
    }
#pragma unroll
    for (int mi = 0; mi < 4; ++mi)
#pragma unroll
      for (int ni = 0; ni < 4; ++ni)
        acc[mi][ni] = __builtin_amdgcn_mfma_f32_16x16x32_bf16(af[mi], bfr[ni], acc[mi][ni], 0, 0, 0);
    __syncthreads();
  }

#pragma unroll
  for (int ni = 0; ni < 4; ++ni) {
    int col = nt * 128 + wc * 64 + ni * 16 + lr;
    float bv = bias[col];
#pragma unroll
    for (int mi = 0; mi < 4; ++mi) {
      int row0 = mt * 128 + wr * 64 + mi * 16 + lg * 4;
#pragma unroll
      for (int r = 0; r < 4; ++r) {
        float v = acc[mi][ni][r] + bv;
        if (ACT == 1) v = 0.5f * v * (1.0f + erff(v * 0.70710678118654752f));  // exact GELU
        if (OB16) ((short*)out)[(size_t)(row0 + r) * N + col] = f2bf(v);
        else      ((float*)out)[(size_t)(row0 + r) * N + col] = v;
      }
    }
  }
}

template <int K, int ACT, bool OB16>
__global__ void gemm_kernel(const short* __restrict__ A, const short* __restrict__ Wt,
                            const float* __restrict__ bias, const int* __restrict__ eidx,
                            char* __restrict__ out, int N) {
  const int nt = blockIdx.x, mt = blockIdx.y, b = blockIdx.z;
  const int e = eidx[b];
  gemm_tile<K, ACT, OB16>(A + (size_t)b * CS * K,
                          Wt + (size_t)e * N * K,
                          bias + (size_t)e * N,
                          out + (size_t)b * CS * N * (OB16 ? 2 : 4), N, mt, nt);
}

// QKV fused: grid (18, 4, 8); nt/6 selects Q/K/V
__global__ void qkv_kernel(const short* __restrict__ Xb,
                           const short* __restrict__ Wqt, const short* __restrict__ Wkt,
                           const short* __restrict__ Wvt,
                           const float* __restrict__ bq, const float* __restrict__ bk,
                           const float* __restrict__ bv,
                           const int* __restrict__ eidx,
                           short* __restrict__ Qb, short* __restrict__ Kb, short* __restrict__ Vb) {
  const int nt = blockIdx.x, mt = blockIdx.y, b = blockIdx.z;
  const int sel = nt / 6, ntl = nt % 6;
  const int e = eidx[b];
  const short* Wt  = (sel == 0) ? Wqt : (sel == 1) ? Wkt : Wvt;
  const float* bia = (sel == 0) ? bq  : (sel == 1) ? bk  : bv;
  short* outp      = (sel == 0) ? Qb  : (sel == 1) ? Kb  : Vb;
  gemm_tile<CH, 0, true>(Xb + (size_t)b * CS * CH, Wt + (size_t)e * CH * CH,
                         bia + (size_t)e * CH,
                         (void*)(outp + (size_t)b * CS * CH), CH, mt, ntl);
}

// ---------------- fused attention ----------------
// grid (B*NH, S/64), block 256 (4 waves x 16 q-rows). KT=32 per tile.
// softmax without max-subtraction (scores are O(1) here; mask is additive).
__global__ void attn_kernel(const short* __restrict__ Qb, const short* __restrict__ Kb,
                            const short* __restrict__ Vb, const float* __restrict__ mask,
                            short* __restrict__ ctx) {
  __shared__ __align__(16) short Vt[2][64 * 40];     // V^T tile, padded stride 40
  __shared__ __align__(16) short Pt[4][2][16 * 40];  // per-wave P tile, double buffered
  const int bh = blockIdx.x;
  const int b = bh / CNH, h = bh % CNH;
  const int qt = blockIdx.y;
  const int t = threadIdx.x, w = t >> 6, l = t & 63, lr = l & 15, lg = l >> 4;

  const size_t bS = (size_t)b * CS;
  const short* Qh = Qb + bS * CH + h * CDH;
  const short* Kh = Kb + bS * CH + h * CDH;
  const short* Vh = Vb + bS * CH + h * CDH;
  const float* mrow = mask + bS;

  const int qrow = qt * 64 + w * 16 + lr;
  bf16x8 qa[2];
  qa[0] = *(const bf16x8*)(Qh + (size_t)qrow * CH + lg * 8);
  qa[1] = *(const bf16x8*)(Qh + (size_t)qrow * CH + 32 + lg * 8);

  f32x4 o[4] = {};
  float lp[4] = {0.f, 0.f, 0.f, 0.f};

  const int dh = t & 63, kg = t >> 6;
  // stage V^T tile 0
  {
    short v8[8];
#pragma unroll
    for (int j = 0; j < 8; ++j) v8[j] = Vh[(size_t)(kg * 8 + j) * CH + dh];
    uint32_t p0 = (uint32_t)(uint16_t)v8[0] | ((uint32_t)(uint16_t)v8[1] << 16);
    uint32_t p1 = (uint32_t)(uint16_t)v8[2] | ((uint32_t)(uint16_t)v8[3] << 16);
    uint32_t p2 = (uint32_t)(uint16_t)v8[4] | ((uint32_t)(uint16_t)v8[5] << 16);
    uint32_t p3 = (uint32_t)(uint16_t)v8[6] | ((uint32_t)(uint16_t)v8[7] << 16);
    uint4 pk = {p0, p1, p2, p3};
    *(uint4*)(&Vt[0][dh * 40 + kg * 8]) = pk;
  }

  for (int tt = 0; tt < CS / 32; ++tt) {
    const int k0 = tt * 32;
    __syncthreads();  // Vt[tt&1] ready (and prior readers of the buffer we stage next are done)

    // S = (Q K^T) for 16q x 32k
    f32x4 sacc[2] = {};
#pragma unroll
    for (int n = 0; n < 2; ++n) {
      bf16x8 kb0 = *(const bf16x8*)(Kh + (size_t)(k0 + n * 16 + lr) * CH + lg * 8);
      bf16x8 kb1 = *(const bf16x8*)(Kh + (size_t)(k0 + n * 16 + lr) * CH + 32 + lg * 8);
      sacc[n] = __builtin_amdgcn_mfma_f32_16x16x32_bf16(qa[0], kb0, sacc[n], 0, 0, 0);
      sacc[n] = __builtin_amdgcn_mfma_f32_16x16x32_bf16(qa[1], kb1, sacc[n], 0, 0, 0);
    }

    // stage next V^T tile (other buffer)
    if (tt + 1 < CS / 32) {
      const int k1 = k0 + 32;
      short v8[8];
#pragma unroll
      for (int j = 0; j < 8; ++j) v8[j] = Vh[(size_t)(k1 + kg * 8 + j) * CH + dh];
      uint32_t p0 = (uint32_t)(uint16_t)v8[0] | ((uint32_t)(uint16_t)v8[1] << 16);
      uint32_t p1 = (uint32_t)(uint16_t)v8[2] | ((uint32_t)(uint16_t)v8[3] << 16);
      uint32_t p2 = (uint32_t)(uint16_t)v8[4] | ((uint32_t)(uint16_t)v8[5] << 16);
      uint32_t p3 = (uint32_t)(uint16_t)v8[6] | ((uint32_t)(uint16_t)v8[7] << 16);
      uint4 pk = {p0, p1, p2, p3};
      *(uint4*)(&Vt[(tt + 1) & 1][dh * 40 + kg * 8]) = pk;
    }

    // exp + row-sum + P -> wave-private LDS (layout [q][kpos], stride 40)
    const int pb = tt & 1;
#pragma unroll
    for (int n = 0; n < 2; ++n) {
      float mv = mrow[k0 + n * 16 + lr];
#pragma unroll
      for (int r = 0; r < 4; ++r) {
        float s = sacc[n][r] * 0.125f + mv;  // 1/sqrt(64)
        float e = __expf(s);
        lp[r] += e;
        Pt[w][pb][(lg * 4 + r) * 40 + n * 16 + lr] = f2bf(e);
      }
    }

    // PV: A = P[16q,32k] frag, B = V[32k,16dh] frags from V^T LDS
    bf16x8 pa = *(const bf16x8*)(&Pt[w][pb][lr * 40 + lg * 8]);
#pragma unroll
    for (int d = 0; d < 4; ++d) {
      bf16x8 vbf = *(const bf16x8*)(&Vt[tt & 1][(d * 16 + lr) * 40 + lg * 8]);
      o[d] = __builtin_amdgcn_mfma_f32_16x16x32_bf16(pa, vbf, o[d], 0, 0, 0);
    }
  }

  // row-sum reduce across the 16 lanes of each lg-group
#pragma unroll
  for (int r = 0; r < 4; ++r) {
    float s = lp[r];
    s += __shfl_xor(s, 1); s += __shfl_xor(s, 2);
    s += __shfl_xor(s, 4); s += __shfl_xor(s, 8);
    lp[r] = 1.0f / s;
  }
#pragma unroll
  for (int d = 0; d < 4; ++d)
#pragma unroll
    for (int r = 0; r < 4; ++r) {
      int row = qt * 64 + w * 16 + lg * 4 + r;
      ctx[(bS + row) * CH + h * CDH + d * 16 + lr] = f2bf(o[d][r] * lp[r]);
    }
}

// ---------------- residual + LayerNorm (1 wave per row) ----------------
__global__ void ln_kernel(const float* __restrict__ xin, const float* __restrict__ res,
                          const float* __restrict__ g, const float* __restrict__ bta,
                          float* __restrict__ out32, short* __restrict__ out16) {
  const int row = blockIdx.x;
  const int l = threadIdx.x;  // 64 threads
  const float* xr = xin + (size_t)row * CH;
  const float* rr = res + (size_t)row * CH;
  float4 v[3];
  float sum = 0.f, ss = 0.f;
#pragma unroll
  for (int j = 0; j < 3; ++j) {
    float4 a = *(const float4*)(xr + j * 256 + l * 4);
    float4 b = *(const float4*)(rr + j * 256 + l * 4);
    a.x += b.x; a.y += b.y; a.z += b.z; a.w += b.w;
    v[j] = a;
    sum += a.x + a.y + a.z + a.w;
    ss  += a.x * a.x + a.y * a.y + a.z * a.z + a.w * a.w;
  }
#pragma unroll
  for (int m = 1; m < 64; m <<= 1) { sum += __shfl_xor(sum, m); ss += __shfl_xor(ss, m); }
  const float mean = sum * (1.0f / CH);
  const float var  = ss * (1.0f / CH) - mean * mean;
  const float rstd = rsqrtf(var + 1e-12f);
#pragma unroll
  for (int j = 0; j < 3; ++j) {
    float4 gg = *(const float4*)(g   + j * 256 + l * 4);
    float4 bb = *(const float4*)(bta + j * 256 + l * 4);
    float4 a = v[j], y;
    y.x = (a.x - mean) * rstd * gg.x + bb.x;
    y.y = (a.y - mean) * rstd * gg.y + bb.y;
    y.z = (a.z - mean) * rstd * gg.z + bb.z;
    y.w = (a.w - mean) * rstd * gg.w + bb.w;
    *(float4*)(out32 + (size_t)row * CH + j * 256 + l * 4) = y;
    if (out16) {
      short4 o;
      o.x = f2bf(y.x); o.y = f2bf(y.y); o.z = f2bf(y.z); o.w = f2bf(y.w);
      *(short4*)(out16 + (size_t)row * CH + j * 256 + l * 4) = o;
    }
  }
}

// ---------------- launcher ----------------
extern "C" void kernel_launch(void* const* d_in, const int* in_sizes, int n_in,
                              void* d_out, int out_size, void* d_ws, size_t ws_size,
                              hipStream_t stream) {
  (void)in_sizes; (void)n_in; (void)out_size; (void)ws_size;
  const float* hidden = (const float*)d_in[0];
  const int*   eidx   = (const int*)d_in[1];
  const float* mask   = (const float*)d_in[2];
  const float* Wq   = (const float*)d_in[3];
  const float* bq   = (const float*)d_in[4];
  const float* Wk   = (const float*)d_in[5];
  const float* bk   = (const float*)d_in[6];
  const float* Wv   = (const float*)d_in[7];
  const float* bv   = (const float*)d_in[8];
  const float* Wo   = (const float*)d_in[9];
  const float* bo   = (const float*)d_in[10];
  const float* ln1g = (const float*)d_in[11];
  const float* ln1b = (const float*)d_in[12];
  const float* Wi   = (const float*)d_in[13];
  const float* bi   = (const float*)d_in[14];
  const float* Wout = (const float*)d_in[15];
  const float* bout = (const float*)d_in[16];
  const float* ln2g = (const float*)d_in[17];
  const float* ln2b = (const float*)d_in[18];

  char* ws = (char*)d_ws;
  size_t off = 0;
  auto alloc = [&](size_t bytes) {
    void* p = ws + off;
    off += (bytes + 255) & ~(size_t)255;
    return p;
  };
  const size_t ACT2 = (size_t)CB * CS * CH * 2;  // bf16 activation buffer, 6.29 MB
  short* Xb   = (short*)alloc(ACT2);
  short* Qb   = (short*)alloc(ACT2);
  short* Kb   = (short*)alloc(ACT2);            // Qb+Kb contiguous -> reused as ffn f32
  short* Vb   = (short*)alloc(ACT2);
  short* ctxb = (short*)alloc(ACT2);            // Vb+ctxb contiguous -> reused as x1 f32
  char*  bigF = (char*)alloc((size_t)CB * CS * CFF * 2);  // attn_out f32 then hmid bf16
  short* Wqt  = (short*)alloc((size_t)CE * CH * CH * 2);
  short* Wkt  = (short*)alloc((size_t)CE * CH * CH * 2);
  short* Wvt  = (short*)alloc((size_t)CE * CH * CH * 2);
  short* Wot  = (short*)alloc((size_t)CE * CH * CH * 2);
  short* Wit  = (short*)alloc((size_t)CE * CH * CFF * 2);
  short* Wo2t = (short*)alloc((size_t)CE * CFF * CH * 2);
  // region aliases (lifetimes are disjoint, see schedule)
  float* attn_out = (float*)bigF;
  short* hmid     = (short*)bigF;
  float* x1       = (float*)Vb;
  short* x1b      = Xb;
  float* ffn      = (float*)Qb;

  // 1. hidden -> bf16
  const int n4 = CB * CS * CH / 4;
  cvt_bf16_kernel<<<(n4 + 255) / 256, 256, 0, stream>>>(hidden, Xb, n4);
  // 2. weights -> bf16 [E][N][K]
  tpose_cvt_kernel<<<dim3(CH / 64, CH / 64, CE), 256, 0, stream>>>(Wq, Wqt, CH, CH);
  tpose_cvt_kernel<<<dim3(CH / 64, CH / 64, CE), 256, 0, stream>>>(Wk, Wkt, CH, CH);
  tpose_cvt_kernel<<<dim3(CH / 64, CH / 64, CE), 256, 0, stream>>>(Wv, Wvt, CH, CH);
  tpose_cvt_kernel<<<dim3(CH / 64, CH / 64, CE), 256, 0, stream>>>(Wo, Wot, CH, CH);
  tpose_cvt_kernel<<<dim3(CFF / 64, CH / 64, CE), 256, 0, stream>>>(Wi, Wit, CH, CFF);
  tpose_cvt_kernel<<<dim3(CH / 64, CFF / 64, CE), 256, 0, stream>>>(Wout, Wo2t, CFF, CH);
  // 3. QKV
  qkv_kernel<<<dim3(18, 4, CB), 256, 0, stream>>>(Xb, Wqt, Wkt, Wvt, bq, bk, bv, eidx, Qb, Kb, Vb);
  // 4. attention
  attn_kernel<<<dim3(CB * CNH, CS / 64), 256, 0, stream>>>(Qb, Kb, Vb, mask, ctxb);
  // 5. O projection (fp32 out)
  gemm_kernel<CH, 0, false><<<dim3(6, 4, CB), 256, 0, stream>>>(ctxb, Wot, bo, eidx, (char*)attn_out, CH);
  // 6. LN1 (residual = hidden), emits fp32 x1 + bf16 x1b
  ln_kernel<<<CB * CS, 64, 0, stream>>>(attn_out, hidden, ln1g, ln1b, x1, x1b);
  // 7. FFN intermediate + GELU (bf16 out)
  gemm_kernel<CH, 1, true><<<dim3(24, 4, CB), 256, 0, stream>>>(x1b, Wit, bi, eidx, (char*)hmid, CFF);
  // 8. FFN output (fp32 out)
  gemm_kernel<CFF, 0, false><<<dim3(6, 4, CB), 256, 0, stream>>>(hmid, Wo2t, bout, eidx, (char*)ffn, CH);
  // 9. LN2 (residual = x1) -> d_out
  ln_kernel<<<CB * CS, 64, 0, stream>>>(ffn, x1, ln2g, ln2b, (float*)d_out, nullptr);
}

// Round 2
// 236.225 us; speedup vs baseline: 1.0270x; 1.0270x over previous
//
#include <hip/hip_runtime.h>
#include <cstdint>
#include <cstddef>

// ---------------- problem constants ----------------
constexpr int CB  = 8;     // batch
constexpr int CS  = 512;   // seq len
constexpr int CH  = 768;   // hidden
constexpr int CNH = 12;    // heads
constexpr int CDH = 64;    // head dim
constexpr int CFF = 3072;  // ffn dim
constexpr int CE  = 4;     // experts

using f32x4  = __attribute__((ext_vector_type(4))) float;
using bf16x8 = __attribute__((ext_vector_type(8))) short;

__device__ __forceinline__ short f2bf(float x) {
  union { float f; uint32_t u; } v; v.f = x;
  return (short)((v.u + 0x7fffu + ((v.u >> 16) & 1u)) >> 16);  // RNE
}

__device__ __forceinline__ void gload_lds16(const void* g, void* l) {
  __builtin_amdgcn_global_load_lds((const __attribute__((address_space(1))) void*)g,
                                   (__attribute__((address_space(3))) void*)l,
                                   16, 0, 0);
}

#define VMCNT(n)  asm volatile("s_waitcnt vmcnt(" #n ")" ::: "memory")

// ---------------- fp32 -> bf16 elementwise ----------------
__global__ void cvt_bf16_kernel(const float* __restrict__ in, short* __restrict__ out, int n4) {
  int i = blockIdx.x * blockDim.x + threadIdx.x;
  if (i < n4) {
    float4 v = ((const float4*)in)[i];
    short4 o;
    o.x = f2bf(v.x); o.y = f2bf(v.y); o.z = f2bf(v.z); o.w = f2bf(v.w);
    ((short4*)out)[i] = o;
  }
}

// ---------------- W [E,K,N] fp32 -> Wt [E,N,K] bf16 (transpose + convert) ----
// grid: (N/64, K/64, E), block 256
__global__ void tpose_cvt_kernel(const float* __restrict__ W, short* __restrict__ Wt,
                                 int K, int N) {
  __shared__ __align__(16) short Ts[64 * 68];
  const int e  = blockIdx.z;
  const int n0 = blockIdx.x * 64, k0 = blockIdx.y * 64;
  const float* Wb = W + (size_t)e * K * N;
  short* Wtb = Wt + (size_t)e * K * N;
  const int t  = threadIdx.x;
  const int tn = t & 15, tk = t >> 4;
#pragma unroll
  for (int p = 0; p < 4; ++p) {
    int k = k0 + p * 16 + tk;
    float4 v = *(const float4*)(Wb + (size_t)k * N + n0 + tn * 4);
#pragma unroll
    for (int j = 0; j < 4; ++j)
      Ts[(tn * 4 + j) * 68 + p * 16 + tk] = f2bf(((const float*)&v)[j]);
  }
  __syncthreads();
#pragma unroll
  for (int p = 0; p < 4; ++p) {
    int n = n0 + p * 16 + tk;
    uint2 o = *(const uint2*)(Ts + (p * 16 + tk) * 68 + tn * 4);
    *(uint2*)(Wtb + (size_t)n * K + k0 + tn * 4) = o;
  }
}

// ---------------- GEMM core (pipelined) ----------------
// out[512,N] = act(A[512,K] @ W^T(stored [N,K]) + bias)
// 128x128 tile, BK=32, 4 waves (2x2 of 64x64).
// 3-deep LDS pipeline, counted vmcnt (T3+T4), read swizzle (T2), setprio (T5).
template <int K, int ACT, bool OB16>
__device__ __forceinline__ void gemm_tile(const short* __restrict__ A,   // sample base [512,K]
                                          const short* __restrict__ Wt,  // expert base [N,K]
                                          const float* __restrict__ bias,// expert base [N]
                                          void* out,                     // sample base [512,N]
                                          int N, int mt, int nt) {
  constexpr int NT = K / 32;            // K-steps (>= 24 for all our shapes)
  __shared__ __align__(16) short As[3][128 * 32];
  __shared__ __align__(16) short Bs[3][128 * 32];
  const int t = threadIdx.x;
  const int w = t >> 6, l = t & 63;
  const int lr = l & 15, lg = l >> 4;

  // --- staging: linear LDS dest (global_load_lds writes base+lane*16),
  //     source column pre-swizzled: slot ^= (row>>1)&3  (rule #21: same XOR on read)
  const int srow = w * 16 + (l >> 2);                  // row within 64-row half
  const int scol = ((l & 3) ^ ((l >> 3) & 3)) * 8;     // swizzled k-element offset
  const short* aS0 = A  + (size_t)(mt * 128 +      srow) * K + scol;
  const short* aS1 = A  + (size_t)(mt * 128 + 64 + srow) * K + scol;
  const short* bS0 = Wt + (size_t)(nt * 128 +      srow) * K + scol;
  const short* bS1 = Wt + (size_t)(nt * 128 + 64 + srow) * K + scol;
  const int dOff = w * 512 + l * 8;                    // linear dest (shorts)

  const int wr = w >> 1, wc = w & 1;
  f32x4 acc[4][4] = {};
  // --- frag read offsets with matching swizzle
  int aoff[4], boff[4];
#pragma unroll
  for (int i = 0; i < 4; ++i) {
    int swz = (lg ^ ((lr >> 1) & 3)) * 8;
    aoff[i] = (wr * 64 + i * 16 + lr) * 32 + swz;
    boff[i] = (wc * 64 + i * 16 + lr) * 32 + swz;
  }

  auto STAGE = [&](int buf, int ti) {
    const int ko = ti * 32;
    gload_lds16(aS0 + ko, &As[buf][dOff]);
    gload_lds16(aS1 + ko, &As[buf][2048 + dOff]);
    gload_lds16(bS0 + ko, &Bs[buf][dOff]);
    gload_lds16(bS1 + ko, &Bs[buf][2048 + dOff]);
  };
  auto COMPUTE = [&](int buf) {
    const short* Ab = &As[buf][0];
    const short* Bb = &Bs[buf][0];
    bf16x8 af[4], bfr[4];
#pragma unroll
    for (int i = 0; i < 4; ++i) {
      af[i]  = *(const bf16x8*)(Ab + aoff[i]);
      bfr[i] = *(const bf16x8*)(Bb + boff[i]);
    }
    __builtin_amdgcn_s_setprio(1);
#pragma unroll
    for (int mi = 0; mi < 4; ++mi)
#pragma unroll
      for (int ni = 0; ni < 4; ++ni)
        acc[mi][ni] = __builtin_amdgcn_mfma_f32_16x16x32_bf16(af[mi], bfr[ni], acc[mi][ni], 0, 0, 0);
    __builtin_amdgcn_s_setprio(0);
  };

  // prologue: fill 3-deep pipeline (12 vmem ops/wave in flight)
  STAGE(0, 0); STAGE(1, 1); STAGE(2, 2);

  for (int tt = 0; tt < NT - 2; ++tt) {
    VMCNT(8);                               // stage-tt's 4 loads done; 8 stay in flight
    __builtin_amdgcn_s_barrier();           // all waves' stage-tt writes visible
    __builtin_amdgcn_sched_barrier(0);
    COMPUTE(tt % 3);
    __builtin_amdgcn_s_barrier();           // all waves done reading buf before restage
    __builtin_amdgcn_sched_barrier(0);
    if (tt + 3 < NT) STAGE(tt % 3, tt + 3);
  }
  // tail: drain 4 -> 0
  VMCNT(4);
  __builtin_amdgcn_s_barrier();
  __builtin_amdgcn_sched_barrier(0);
  COMPUTE((NT - 2) % 3);
  VMCNT(0);
  __builtin_amdgcn_s_barrier();
  __builtin_amdgcn_sched_barrier(0);
  COMPUTE((NT - 1) % 3);

  // epilogue
#pragma unroll
  for (int ni = 0; ni < 4; ++ni) {
    int col = nt * 128 + wc * 64 + ni * 16 + lr;
    float bv = bias[col];
#pragma unroll
    for (int mi = 0; mi < 4; ++mi) {
      int row0 = mt * 128 + wr * 64 + mi * 16 + lg * 4;
#pragma unroll
      for (int r = 0; r < 4; ++r) {
        float v = acc[mi][ni][r] + bv;
        if (ACT == 1) v = 0.5f * v * (1.0f + erff(v * 0.70710678118654752f));  // exact GELU
        if (OB16) ((short*)out)[(size_t)(row0 + r) * N + col] = f2bf(v);
        else      ((float*)out)[(size_t)(row0 + r) * N + col] = v;
      }
    }
  }
}

// XCD-grouped 1-D grid decode: the 4 mt-tiles sharing one B-panel land on the
// same XCD (launch-ids stride 8 apart). G = NTn*CB groups, G%8==0 since CB=8.
template <int NTn>
__device__ __forceinline__ void grid_decode(int& nt, int& mt, int& b) {
  const int L = blockIdx.x;
  const int xcd = L & 7, r = L >> 3;
  mt = r & 3;
  const int g = (r >> 2) * 8 + xcd;
  nt = g % NTn; b = g / NTn;
}

template <int K, int ACT, bool OB16, int NTn>
__global__ __launch_bounds__(256, 3)
void gemm_kernel(const short* __restrict__ A, const short* __restrict__ Wt,
                 const float* __restrict__ bias, const int* __restrict__ eidx,
                 char* __restrict__ out, int N) {
  int nt, mt, b;
  grid_decode<NTn>(nt, mt, b);
  const int e = eidx[b];
  gemm_tile<K, ACT, OB16>(A + (size_t)b * CS * K,
                          Wt + (size_t)e * N * K,
                          bias + (size_t)e * N,
                          out + (size_t)b * CS * N * (OB16 ? 2 : 4), N, mt, nt);
}

// QKV fused: 1-D grid 18*4*8; nt/6 selects Q/K/V
__global__ __launch_bounds__(256, 3)
void qkv_kernel(const short* __restrict__ Xb,
                const short* __restrict__ Wqt, const short* __restrict__ Wkt,
                const short* __restrict__ Wvt,
                const float* __restrict__ bq, const float* __restrict__ bk,
                const float* __restrict__ bv,
                const int* __restrict__ eidx,
                short* __restrict__ Qb, short* __restrict__ Kb, short* __restrict__ Vb) {
  int nt, mt, b;
  grid_decode<18>(nt, mt, b);
  const int sel = nt / 6, ntl = nt % 6;
  const int e = eidx[b];
  const short* Wt  = (sel == 0) ? Wqt : (sel == 1) ? Wkt : Wvt;
  const float* bia = (sel == 0) ? bq  : (sel == 1) ? bk  : bv;
  short* outp      = (sel == 0) ? Qb  : (sel == 1) ? Kb  : Vb;
  gemm_tile<CH, 0, true>(Xb + (size_t)b * CS * CH, Wt + (size_t)e * CH * CH,
                         bia + (size_t)e * CH,
                         (void*)(outp + (size_t)b * CS * CH), CH, mt, ntl);
}

// ---------------- fused attention ----------------
// grid (B*NH, S/64), block 256 (4 waves x 16 q-rows). KT=32 per tile.
__global__ void attn_kernel(const short* __restrict__ Qb, const short* __restrict__ Kb,
                            const short* __restrict__ Vb, const float* __restrict__ mask,
                            short* __restrict__ ctx) {
  __shared__ __align__(16) short Vt[2][64 * 40];     // V^T tile, padded stride 40
  __shared__ __align__(16) short Pt[4][2][16 * 40];  // per-wave P tile, double buffered
  const int bh = blockIdx.x;
  const int b = bh / CNH, h = bh % CNH;
  const int qt = blockIdx.y;
  const int t = threadIdx.x, w = t >> 6, l = t & 63, lr = l & 15, lg = l >> 4;

  const size_t bS = (size_t)b * CS;
  const short* Qh = Qb + bS * CH + h * CDH;
  const short* Kh = Kb + bS * CH + h * CDH;
  const short* Vh = Vb + bS * CH + h * CDH;
  const float* mrow = mask + bS;

  const int qrow = qt * 64 + w * 16 + lr;
  bf16x8 qa[2];
  qa[0] = *(const bf16x8*)(Qh + (size_t)qrow * CH + lg * 8);
  qa[1] = *(const bf16x8*)(Qh + (size_t)qrow * CH + 32 + lg * 8);

  f32x4 o[4] = {};
  float lp[4] = {0.f, 0.f, 0.f, 0.f};

  const int dh = t & 63, kg = t >> 6;
  {
    short v8[8];
#pragma unroll
    for (int j = 0; j < 8; ++j) v8[j] = Vh[(size_t)(kg * 8 + j) * CH + dh];
    uint32_t p0 = (uint32_t)(uint16_t)v8[0] | ((uint32_t)(uint16_t)v8[1] << 16);
    uint32_t p1 = (uint32_t)(uint16_t)v8[2] | ((uint32_t)(uint16_t)v8[3] << 16);
    uint32_t p2 = (uint32_t)(uint16_t)v8[4] | ((uint32_t)(uint16_t)v8[5] << 16);
    uint32_t p3 = (uint32_t)(uint16_t)v8[6] | ((uint32_t)(uint16_t)v8[7] << 16);
    uint4 pk = {p0, p1, p2, p3};
    *(uint4*)(&Vt[0][dh * 40 + kg * 8]) = pk;
  }

  for (int tt = 0; tt < CS / 32; ++tt) {
    const int k0 = tt * 32;
    __syncthreads();

    f32x4 sacc[2] = {};
#pragma unroll
    for (int n = 0; n < 2; ++n) {
      bf16x8 kb0 = *(const bf16x8*)(Kh + (size_t)(k0 + n * 16 + lr) * CH + lg * 8);
      bf16x8 kb1 = *(const bf16x8*)(Kh + (size_t)(k0 + n * 16 + lr) * CH + 32 + lg * 8);
      sacc[n] = __builtin_amdgcn_mfma_f32_16x16x32_bf16(qa[0], kb0, sacc[n], 0, 0, 0);
      sacc[n] = __builtin_amdgcn_mfma_f32_16x16x32_bf16(qa[1], kb1, sacc[n], 0, 0, 0);
    }

    if (tt + 1 < CS / 32) {
      const int k1 = k0 + 32;
      short v8[8];
#pragma unroll
      for (int j = 0; j < 8; ++j) v8[j] = Vh[(size_t)(k1 + kg * 8 + j) * CH + dh];
      uint32_t p0 = (uint32_t)(uint16_t)v8[0] | ((uint32_t)(uint16_t)v8[1] << 16);
      uint32_t p1 = (uint32_t)(uint16_t)v8[2] | ((uint32_t)(uint16_t)v8[3] << 16);
      uint32_t p2 = (uint32_t)(uint16_t)v8[4] | ((uint32_t)(uint16_t)v8[5] << 16);
      uint32_t p3 = (uint32_t)(uint16_t)v8[6] | ((uint32_t)(uint16_t)v8[7] << 16);
      uint4 pk = {p0, p1, p2, p3};
      *(uint4*)(&Vt[(tt + 1) & 1][dh * 40 + kg * 8]) = pk;
    }

    const int pb = tt & 1;
#pragma unroll
    for (int n = 0; n < 2; ++n) {
      float mv = mrow[k0 + n * 16 + lr];
#pragma unroll
      for (int r = 0; r < 4; ++r) {
        float s = sacc[n][r] * 0.125f + mv;  // 1/sqrt(64)
        float e = __expf(s);
        lp[r] += e;
        Pt[w][pb][(lg * 4 + r) * 40 + n * 16 + lr] = f2bf(e);
      }
    }

    bf16x8 pa = *(const bf16x8*)(&Pt[w][pb][lr * 40 + lg * 8]);
#pragma unroll
    for (int d = 0; d < 4; ++d) {
      bf16x8 vbf = *(const bf16x8*)(&Vt[tt & 1][(d * 16 + lr) * 40 + lg * 8]);
      o[d] = __builtin_amdgcn_mfma_f32_16x16x32_bf16(pa, vbf, o[d], 0, 0, 0);
    }
  }

#pragma unroll
  for (int r = 0; r < 4; ++r) {
    float s = lp[r];
    s += __shfl_xor(s, 1); s += __shfl_xor(s, 2);
    s += __shfl_xor(s, 4); s += __shfl_xor(s, 8);
    lp[r] = 1.0f / s;
  }
#pragma unroll
  for (int d = 0; d < 4; ++d)
#pragma unroll
    for (int r = 0; r < 4; ++r) {
      int row = qt * 64 + w * 16 + lg * 4 + r;
      ctx[(bS + row) * CH + h * CDH + d * 16 + lr] = f2bf(o[d][r] * lp[r]);
    }
}

// ---------------- residual + LayerNorm (1 wave per row) ----------------
__global__ void ln_kernel(const float* __restrict__ xin, const float* __restrict__ res,
                          const float* __restrict__ g, const float* __restrict__ bta,
                          float* __restrict__ out32, short* __restrict__ out16) {
  const int row = blockIdx.x;
  const int l = threadIdx.x;  // 64 threads
  const float* xr = xin + (size_t)row * CH;
  const float* rr = res + (size_t)row * CH;
  float4 v[3];
  float sum = 0.f, ss = 0.f;
#pragma unroll
  for (int j = 0; j < 3; ++j) {
    float4 a = *(const float4*)(xr + j * 256 + l * 4);
    float4 b = *(const float4*)(rr + j * 256 + l * 4);
    a.x += b.x; a.y += b.y; a.z += b.z; a.w += b.w;
    v[j] = a;
    sum += a.x + a.y + a.z + a.w;
    ss  += a.x * a.x + a.y * a.y + a.z * a.z + a.w * a.w;
  }
#pragma unroll
  for (int m = 1; m < 64; m <<= 1) { sum += __shfl_xor(sum, m); ss += __shfl_xor(ss, m); }
  const float mean = sum * (1.0f / CH);
  const float var  = ss * (1.0f / CH) - mean * mean;
  const float rstd = rsqrtf(var + 1e-12f);
#pragma unroll
  for (int j = 0; j < 3; ++j) {
    float4 gg = *(const float4*)(g   + j * 256 + l * 4);
    float4 bb = *(const float4*)(bta + j * 256 + l * 4);
    float4 a = v[j], y;
    y.x = (a.x - mean) * rstd * gg.x + bb.x;
    y.y = (a.y - mean) * rstd * gg.y + bb.y;
    y.z = (a.z - mean) * rstd * gg.z + bb.z;
    y.w = (a.w - mean) * rstd * gg.w + bb.w;
    *(float4*)(out32 + (size_t)row * CH + j * 256 + l * 4) = y;
    if (out16) {
      short4 o;
      o.x = f2bf(y.x); o.y = f2bf(y.y); o.z = f2bf(y.z); o.w = f2bf(y.w);
      *(short4*)(out16 + (size_t)row * CH + j * 256 + l * 4) = o;
    }
  }
}

// ---------------- launcher ----------------
extern "C" void kernel_launch(void* const* d_in, const int* in_sizes, int n_in,
                              void* d_out, int out_size, void* d_ws, size_t ws_size,
                              hipStream_t stream) {
  (void)in_sizes; (void)n_in; (void)out_size; (void)ws_size;
  const float* hidden = (const float*)d_in[0];
  const int*   eidx   = (const int*)d_in[1];
  const float* mask   = (const float*)d_in[2];
  const float* Wq   = (const float*)d_in[3];
  const float* bq   = (const float*)d_in[4];
  const float* Wk   = (const float*)d_in[5];
  const float* bk   = (const float*)d_in[6];
  const float* Wv   = (const float*)d_in[7];
  const float* bv   = (const float*)d_in[8];
  const float* Wo   = (const float*)d_in[9];
  const float* bo   = (const float*)d_in[10];
  const float* ln1g = (const float*)d_in[11];
  const float* ln1b = (const float*)d_in[12];
  const float* Wi   = (const float*)d_in[13];
  const float* bi   = (const float*)d_in[14];
  const float* Wout = (const float*)d_in[15];
  const float* bout = (const float*)d_in[16];
  const float* ln2g = (const float*)d_in[17];
  const float* ln2b = (const float*)d_in[18];

  char* ws = (char*)d_ws;
  size_t off = 0;
  auto alloc = [&](size_t bytes) {
    void* p = ws + off;
    off += (bytes + 255) & ~(size_t)255;
    return p;
  };
  const size_t ACT2 = (size_t)CB * CS * CH * 2;
  short* Xb   = (short*)alloc(ACT2);
  short* Qb   = (short*)alloc(ACT2);
  short* Kb   = (short*)alloc(ACT2);            // Qb+Kb contiguous -> reused as ffn f32
  short* Vb   = (short*)alloc(ACT2);
  short* ctxb = (short*)alloc(ACT2);            // Vb+ctxb contiguous -> reused as x1 f32
  char*  bigF = (char*)alloc((size_t)CB * CS * CFF * 2);
  short* Wqt  = (short*)alloc((size_t)CE * CH * CH * 2);
  short* Wkt  = (short*)alloc((size_t)CE * CH * CH * 2);
  short* Wvt  = (short*)alloc((size_t)CE * CH * CH * 2);
  short* Wot  = (short*)alloc((size_t)CE * CH * CH * 2);
  short* Wit  = (short*)alloc((size_t)CE * CH * CFF * 2);
  short* Wo2t = (short*)alloc((size_t)CE * CFF * CH * 2);
  float* attn_out = (float*)bigF;
  short* hmid     = (short*)bigF;
  float* x1       = (float*)Vb;
  short* x1b      = Xb;
  float* ffn      = (float*)Qb;

  const int n4 = CB * CS * CH / 4;
  cvt_bf16_kernel<<<(n4 + 255) / 256, 256, 0, stream>>>(hidden, Xb, n4);
  tpose_cvt_kernel<<<dim3(CH / 64, CH / 64, CE), 256, 0, stream>>>(Wq, Wqt, CH, CH);
  tpose_cvt_kernel<<<dim3(CH / 64, CH / 64, CE), 256, 0, stream>>>(Wk, Wkt, CH, CH);
  tpose_cvt_kernel<<<dim3(CH / 64, CH / 64, CE), 256, 0, stream>>>(Wv, Wvt, CH, CH);
  tpose_cvt_kernel<<<dim3(CH / 64, CH / 64, CE), 256, 0, stream>>>(Wo, Wot, CH, CH);
  tpose_cvt_kernel<<<dim3(CFF / 64, CH / 64, CE), 256, 0, stream>>>(Wi, Wit, CH, CFF);
  tpose_cvt_kernel<<<dim3(CH / 64, CFF / 64, CE), 256, 0, stream>>>(Wout, Wo2t, CFF, CH);
  // QKV: 18 n-tiles * 4 m-tiles * 8 samples
  qkv_kernel<<<18 * 4 * CB, 256, 0, stream>>>(Xb, Wqt, Wkt, Wvt, bq, bk, bv, eidx, Qb, Kb, Vb);
  attn_kernel<<<dim3(CB * CNH, CS / 64), 256, 0, stream>>>(Qb, Kb, Vb, mask, ctxb);
  // O projection (fp32 out)
  gemm_kernel<CH, 0, false, 6><<<6 * 4 * CB, 256, 0, stream>>>(ctxb, Wot, bo, eidx, (char*)attn_out, CH);
  ln_kernel<<<CB * CS, 64, 0, stream>>>(attn_out, hidden, ln1g, ln1b, x1, x1b);
  // FFN intermediate + GELU (bf16 out)
  gemm_kernel<CH, 1, true, 24><<<24 * 4 * CB, 256, 0, stream>>>(x1b, Wit, bi, eidx, (char*)hmid, CFF);
  // FFN output (fp32 out)
  gemm_kernel<CFF, 0, false, 6><<<6 * 4 * CB, 256, 0, stream>>>(hmid, Wo2t, bout, eidx, (char*)ffn, CH);
  ln_kernel<<<CB * CS, 64, 0, stream>>>(ffn, x1, ln2g, ln2b, (float*)d_out, nullptr);
}